// Round 10
// baseline (989.875 us; speedup 1.0000x reference)
//
#include <hip/hip_runtime.h>
#include <hip/hip_bf16.h>
#include <stdint.h>

typedef unsigned long long u64;
typedef __attribute__((ext_vector_type(8))) short bf16x8;   // 8 bf16 = 4 VGPRs
typedef __attribute__((ext_vector_type(4))) float f32x4;
typedef __attribute__((ext_vector_type(2))) float f32x2;    // v_pk_*_f32 pair

__device__ __forceinline__ unsigned short f2bf(float f) {
    unsigned x = __float_as_uint(f);
    unsigned r = (x + 0x7fffu + ((x >> 16) & 1u)) >> 16;   // RNE
    return (unsigned short)r;
}

// 8 f32 -> bf16x8 via packed RNE converts (v_cvt_pk_bf16_f32).
__device__ __forceinline__ bf16x8 cvt8(float4 a, float4 b) {
    union { bf16x8 v; __hip_bfloat162 h[4]; } u;
    u.h[0] = __float22bfloat162_rn({a.x, a.y});
    u.h[1] = __float22bfloat162_rn({a.z, a.w});
    u.h[2] = __float22bfloat162_rn({b.x, b.y});
    u.h[3] = __float22bfloat162_rn({b.z, b.w});
    return u.v;
}

// Wave64 max-reduce of a non-negative f32 at VALU speed (DPP, no LDS hops).
__device__ __forceinline__ float wave_max_dpp(float v) {
#define DPP_MAX_STEP(ctrl)                                                     \
    v = fmaxf(v, __int_as_float(__builtin_amdgcn_update_dpp(                   \
               0, __float_as_int(v), (ctrl), 0xf, 0xf, true)))
    DPP_MAX_STEP(0xB1);   // quad_perm xor1
    DPP_MAX_STEP(0x4E);   // quad_perm xor2
    DPP_MAX_STEP(0x141);  // row_half_mirror xor4
    DPP_MAX_STEP(0x140);  // row_mirror xor8
    DPP_MAX_STEP(0x142);  // row_bcast15
    DPP_MAX_STEP(0x143);  // row_bcast31
#undef DPP_MAX_STEP
    return __int_as_float(__builtin_amdgcn_readlane(__float_as_int(v), 63));
}

struct WPack { const float* w[9]; const float* b[9]; };

// ---------------------------------------------------------------------------
// Kernel 0: weight prep (separate launch => results are plain-cacheable in
// every XCD L2 via the kernel-boundary release/acquire).
// ---------------------------------------------------------------------------
__global__ __launch_bounds__(256) void prep_kernel(WPack p,
                                                   unsigned short* __restrict__ wout,
                                                   float* __restrict__ bout) {
    constexpr int cin[9]  = {67, 32, 32,  67, 64, 64,  67, 64, 96};
    constexpr int cout[9] = {32, 32, 64,  64, 64, 128, 64, 96, 128};
    constexpr int sw[9]   = {104, 40, 40, 104, 72, 72, 104, 72, 104};
    constexpr int woff[9] = {0, 3328, 4608, 7168, 13824, 18432, 27648, 34304, 41216};
    constexpr int boff[9] = {0, 32, 64, 128, 192, 256, 384, 448, 544};
    const int L = blockIdx.x;
    const float* w = p.w[L];
    const int ci = cin[L], co = cout[L], s = sw[L];
    unsigned short* dst = wout + woff[L];
    for (int e = threadIdx.x; e < co * s; e += 256) {
        const int n = e / s, k = e % s;
        dst[e] = (k < ci) ? f2bf(w[(size_t)k * co + n]) : (unsigned short)0;
    }
    for (int e = threadIdx.x; e < co; e += 256) bout[boff[L] + e] = p.b[L][e];
}

// ---------------------------------------------------------------------------
// Single-radius ball query into LDS (one wave). Bit-exact predicate vs numpy.
// ---------------------------------------------------------------------------
template <int NS>
__device__ __forceinline__ void ballq_one(const float* __restrict__ base,
                                          float cx, float cy, float cz, float R2,
                                          unsigned short* __restrict__ out, int lane) {
    int cnt = 0, f = 0;
    const u64 lower = (((u64)1) << lane) - 1;
    for (int it = 0; it < 64; ++it) {
        const int j = it * 64 + lane;
        const float* p = base + j * 3;
        const float dx = p[0] - cx, dy = p[1] - cy, dz = p[2] - cz;
        const float d2 = __fadd_rn(__fadd_rn(__fmul_rn(dx, dx), __fmul_rn(dy, dy)),
                                   __fmul_rn(dz, dz));
        const bool pr = d2 < R2;
        const u64 m = __ballot(pr);
        if (cnt == 0 && m) f = it * 64 + __builtin_ctzll(m);
        const int pos = cnt + (int)__builtin_popcountll(m & lower);
        if (pr && pos < NS) out[pos] = (unsigned short)j;
        cnt += (int)__builtin_popcountll(m);
        if (cnt >= NS) break;
    }
    for (int pos = cnt + lane; pos < NS; pos += 64) out[pos] = (unsigned short)f;
}

// ---------------------------------------------------------------------------
// Layer 1: A-fragments direct from global points; K = 96 (67 real + pad).
// ---------------------------------------------------------------------------
template <int MW, int Cout, int SOUT>
__device__ __forceinline__ void layer1_direct(
    const float* __restrict__ pts, const float* __restrict__ xyzb,
    const unsigned short* __restrict__ idxb,
    float ncx, float ncy, float ncz,
    const unsigned short* __restrict__ Wg, const float* __restrict__ bg,
    unsigned short* __restrict__ dst, int lane, int mslice) {
    constexpr int SW = 104;
    constexpr int MT = MW / 16;
    constexpr int NT = Cout / 16;
    const int ml = lane & 15;
    const int quad = lane >> 4;

    bf16x8 afr[MT][3];
#pragma unroll
    for (int mt = 0; mt < MT; ++mt) {
        const int row = mslice * MW + mt * 16 + ml;
        const int id = idxb[row] & 4095;
        const float* rb = pts + ((size_t)id << 6) + quad * 8;
        const float4* r4 = reinterpret_cast<const float4*>(rb);
        afr[mt][0] = cvt8(r4[0], r4[1]);
        const float4* r4b = reinterpret_cast<const float4*>(rb + 32);
        afr[mt][1] = cvt8(r4b[0], r4b[1]);
        union { bf16x8 v; unsigned short h[8]; } tg;
        tg.v = (bf16x8)(short)0;
        if (quad == 0) {
            const float* pz = xyzb + (size_t)id * 3;
            tg.h[0] = f2bf(pz[0] - ncx);
            tg.h[1] = f2bf(pz[1] - ncy);
            tg.h[2] = f2bf(pz[2] - ncz);
        }
        afr[mt][2] = tg.v;
    }

    f32x4 acc[MT][NT];
#pragma unroll
    for (int mt = 0; mt < MT; ++mt)
#pragma unroll
        for (int nt = 0; nt < NT; ++nt) acc[mt][nt] = (f32x4){0.f, 0.f, 0.f, 0.f};

#pragma unroll
    for (int ks = 0; ks < 3; ++ks) {
        bf16x8 bfr[NT];
#pragma unroll
        for (int nt = 0; nt < NT; ++nt)
            bfr[nt] = *reinterpret_cast<const bf16x8*>(
                Wg + (nt * 16 + ml) * SW + ks * 32 + quad * 8);
#pragma unroll
        for (int mt = 0; mt < MT; ++mt)
#pragma unroll
            for (int nt = 0; nt < NT; ++nt)
                acc[mt][nt] = __builtin_amdgcn_mfma_f32_16x16x32_bf16(
                    afr[mt][ks], bfr[nt], acc[mt][nt], 0, 0, 0);
    }

#pragma unroll
    for (int nt = 0; nt < NT; ++nt) {
        const int col = nt * 16 + ml;
        const float bv = bg[col];
#pragma unroll
        for (int mt = 0; mt < MT; ++mt)
#pragma unroll
            for (int r = 0; r < 4; ++r) {
                const float v = fmaxf(acc[mt][nt][r] + bv, 0.0f);
                dst[(mslice * MW + mt * 16 + quad * 4 + r) * SOUT + col] = f2bf(v);
            }
    }
}

// ---------------------------------------------------------------------------
// Layers 2/3: A from LDS, B + bias from prepped global.
// LAST+DIRECT: quad0 lanes write outfeat straight (WPG==1 branches).
// LAST+!DIRECT: atomicMax into LDS Mx (WPG==4 cross-wave merge).
// ---------------------------------------------------------------------------
template <int MW, int Kp, int Cout, int SIN, int SW, int SOUT, bool LAST, bool DIRECT>
__device__ __forceinline__ void layer_lds(const unsigned short* __restrict__ src,
                                          unsigned short* __restrict__ dst,
                                          const unsigned short* __restrict__ Wg,
                                          const float* __restrict__ bg,
                                          float* __restrict__ Mx,
                                          float* __restrict__ outp,
                                          int lane, int mslice) {
    constexpr int MT = MW / 16;
    constexpr int NT = Cout / 16;
    const int ml = lane & 15;
    const int quad = lane >> 4;

    f32x4 acc[MT][NT];
#pragma unroll
    for (int mt = 0; mt < MT; ++mt)
#pragma unroll
        for (int nt = 0; nt < NT; ++nt) acc[mt][nt] = (f32x4){0.f, 0.f, 0.f, 0.f};

#pragma unroll
    for (int ks = 0; ks < Kp; ks += 32) {
        bf16x8 afr[MT], bfr[NT];
#pragma unroll
        for (int mt = 0; mt < MT; ++mt)
            afr[mt] = *reinterpret_cast<const bf16x8*>(
                src + (mslice * MW + mt * 16 + ml) * SIN + ks + quad * 8);
#pragma unroll
        for (int nt = 0; nt < NT; ++nt)
            bfr[nt] = *reinterpret_cast<const bf16x8*>(
                Wg + (nt * 16 + ml) * SW + ks + quad * 8);
#pragma unroll
        for (int mt = 0; mt < MT; ++mt)
#pragma unroll
            for (int nt = 0; nt < NT; ++nt)
                acc[mt][nt] = __builtin_amdgcn_mfma_f32_16x16x32_bf16(
                    afr[mt], bfr[nt], acc[mt][nt], 0, 0, 0);
    }

#pragma unroll
    for (int nt = 0; nt < NT; ++nt) {
        const int col = nt * 16 + ml;
        const float bv = bg[col];
        if constexpr (!LAST) {
#pragma unroll
            for (int mt = 0; mt < MT; ++mt)
#pragma unroll
                for (int r = 0; r < 4; ++r) {
                    const float v = fmaxf(acc[mt][nt][r] + bv, 0.0f);
                    dst[(mslice * MW + mt * 16 + quad * 4 + r) * SOUT + col] = f2bf(v);
                }
        } else {
            float mx = 0.0f;   // relu floor folds into the max
#pragma unroll
            for (int mt = 0; mt < MT; ++mt)
#pragma unroll
                for (int r = 0; r < 4; ++r) mx = fmaxf(mx, acc[mt][nt][r] + bv);
            mx = fmaxf(mx, __shfl_xor(mx, 16, 64));
            mx = fmaxf(mx, __shfl_xor(mx, 32, 64));
            if constexpr (DIRECT) {
                if (quad == 0) outp[col] = mx;
            } else {
                if (quad == 0)
                    atomicMax(reinterpret_cast<int*>(Mx + col), __float_as_int(mx));
            }
        }
    }
}

// ---------------------------------------------------------------------------
// One work item: NG groups (WPG==1 -> 4 groups, 1 wave each; WPG==4 -> 1 group,
// 4 waves). Inline ballq into LDS + 3-layer MLP + pooled write.
// ---------------------------------------------------------------------------
template <int NS, int C1, int C2, int C3, int WPG, int CH_OFF>
__device__ __forceinline__ void do_item(
    char* smem, const float* __restrict__ xyz, const float* __restrict__ points,
    float* newxyz, float* __restrict__ outfeat,
    const unsigned short* __restrict__ wg1, const unsigned short* __restrict__ wg2,
    const unsigned short* __restrict__ wg3,
    const float* __restrict__ bg1, const float* __restrict__ bg2,
    const float* __restrict__ bg3,
    float R2, int b, int p, int tid, int lane, int wave) {
    constexpr int SB = C1 + 8;
    constexpr int SC = C2 + 8;
    constexpr int MW = NS / WPG;
    unsigned short* idxb = (unsigned short*)smem;                    // <=1KB
    unsigned short* Bb = (unsigned short*)(smem + 1024);             // <=18432B
    unsigned short* Cb = (unsigned short*)(smem + 1024 + 18432);     // <=26624B
    float* Mx = (float*)(smem + 1024 + 18432 + 26624);               // <=512B

    const int gl = (WPG == 1) ? wave : 0;
    const int mslice = (WPG == 1) ? 0 : wave;
    const int g = b * 1024 + ((WPG == 1) ? p * 4 + wave : p);
    const float* base = xyz + (size_t)b * 12288;

    // centroid: LLC reads (producer used agent-scope stores)
    const float ncx = __hip_atomic_load(&newxyz[(size_t)g * 3 + 0],
                                        __ATOMIC_RELAXED, __HIP_MEMORY_SCOPE_AGENT);
    const float ncy = __hip_atomic_load(&newxyz[(size_t)g * 3 + 1],
                                        __ATOMIC_RELAXED, __HIP_MEMORY_SCOPE_AGENT);
    const float ncz = __hip_atomic_load(&newxyz[(size_t)g * 3 + 2],
                                        __ATOMIC_RELAXED, __HIP_MEMORY_SCOPE_AGENT);

    // ball query into LDS (WPG==4: all 4 waves write identical values — benign)
    unsigned short* myidx = idxb + gl * NS;
    ballq_one<NS>(base, ncx, ncy, ncz, R2, myidx, lane);
    if (WPG == 4)
        for (int e = tid; e < C3; e += 256) Mx[e] = 0.0f;
    __syncthreads();

    float* outp = outfeat + (size_t)g * 320 + CH_OFF;
    layer1_direct<MW, C1, SB>(points + ((size_t)b << 18), base, myidx,
                              ncx, ncy, ncz, wg1, bg1, Bb + gl * NS * SB,
                              lane, mslice);
    layer_lds<MW, C1, C2, SB, C1 + 8, SC, false, false>(
        Bb + gl * NS * SB, Cb + gl * NS * SC, wg2, bg2, nullptr, nullptr,
        lane, mslice);
    layer_lds<MW, C2, C3, SC, C2 + 8, 0, true, (WPG == 1)>(
        Cb + gl * NS * SC, nullptr, wg3, bg3, Mx, outp, lane, mslice);

    if (WPG == 4) {
        __syncthreads();
        for (int e = tid; e < C3; e += 256) outp[e] = Mx[e];
    }
}

// ---------------------------------------------------------------------------
// Fused pipeline kernel. Blocks 0..7: FPS producer (R7 structure, unchanged
// math) publishing centroids (agent-scope stores) + release flag every 32
// iters. Blocks 8..G-1: flag-gated workers over 12288 items ordered by
// required centroid index. Grid <= queried occupancy => all blocks resident.
// ---------------------------------------------------------------------------
__global__ __launch_bounds__(256) void fused_kernel(
    const float* __restrict__ xyz, const float* __restrict__ points,
    float* newxyz, float* __restrict__ outfeat,
    const unsigned short* __restrict__ wprep, const float* __restrict__ bprep,
    int* progress, int W) {
#pragma clang fp contract(off)
    __shared__ __align__(16) char smem[49664];
    const int tid = threadIdx.x;
    const int lane = tid & 63;
    const int wave = tid >> 6;

    if (blockIdx.x >= 8) {   // ================= worker =================
        const int wid = blockIdx.x - 8;
        for (int s = wid; s < 12288; s += W) {
            int br, b, p;
            if (s < 6144) {
                p = s / 24;
                const int r = s % 24;
                br = r >> 3;
                b = r & 7;
            } else {
                const int q = s - 6144;
                p = 256 + (q >> 3);
                b = q & 7;
                br = 2;
            }
            const int kmax = (br == 2) ? p : p * 4 + 3;
            while (__hip_atomic_load(&progress[b * 32], __ATOMIC_RELAXED,
                                     __HIP_MEMORY_SCOPE_AGENT) <= kmax)
                __builtin_amdgcn_s_sleep(32);
            __atomic_signal_fence(__ATOMIC_SEQ_CST);   // no load hoisting

            if (br == 0)
                do_item<16, 32, 32, 64, 1, 0>(smem, xyz, points, newxyz, outfeat,
                    wprep + 0, wprep + 3328, wprep + 4608,
                    bprep + 0, bprep + 32, bprep + 64,
                    0.01f, b, p, tid, lane, wave);
            else if (br == 1)
                do_item<32, 64, 64, 128, 1, 64>(smem, xyz, points, newxyz, outfeat,
                    wprep + 7168, wprep + 13824, wprep + 18432,
                    bprep + 128, bprep + 192, bprep + 256,
                    0.04f, b, p, tid, lane, wave);
            else
                do_item<128, 64, 96, 128, 4, 192>(smem, xyz, points, newxyz, outfeat,
                    wprep + 27648, wprep + 34304, wprep + 41216,
                    bprep + 384, bprep + 448, bprep + 544,
                    0.16f, b, p, tid, lane, wave);
            __syncthreads();   // LDS reuse across items
        }
        return;
    }

    // ================= FPS producer (R7-proven structure) =================
    const int b = blockIdx.x;
    const int t = tid;
    float* xs = (float*)smem;
    float* ys = xs + 4096;
    float* zs = ys + 4096;
    u64* skey = (u64*)(smem + 49152);   // [2][4]

    f32x2 px[8], py[8], pz[8], dist[8];
    {
        union { float4 v[12]; float f[48]; } u;
        const float4* src =
            reinterpret_cast<const float4*>(xyz + (size_t)b * 12288) + t * 12;
#pragma unroll
        for (int w = 0; w < 12; ++w) u.v[w] = src[w];
#pragma unroll
        for (int i = 0; i < 8; ++i) {
            px[i] = (f32x2){u.f[6 * i + 0], u.f[6 * i + 3]};
            py[i] = (f32x2){u.f[6 * i + 1], u.f[6 * i + 4]};
            pz[i] = (f32x2){u.f[6 * i + 2], u.f[6 * i + 5]};
            dist[i] = (f32x2){1e10f, 1e10f};
            const int j = t * 16 + 2 * i;
            xs[j] = px[i].x; xs[j + 1] = px[i].y;
            ys[j] = py[i].x; ys[j + 1] = py[i].y;
            zs[j] = pz[i].x; zs[j + 1] = pz[i].y;
        }
    }
    __syncthreads();

    int far = 0;
    for (int k = 0; k < 1024; ++k) {
        const float cx = xs[far], cy = ys[far], cz = zs[far];
        if (t == 0) {
            const size_t o = ((size_t)b * 1024 + k) * 3;
            __hip_atomic_store(&newxyz[o + 0], cx, __ATOMIC_RELAXED,
                               __HIP_MEMORY_SCOPE_AGENT);
            __hip_atomic_store(&newxyz[o + 1], cy, __ATOMIC_RELAXED,
                               __HIP_MEMORY_SCOPE_AGENT);
            __hip_atomic_store(&newxyz[o + 2], cz, __ATOMIC_RELAXED,
                               __HIP_MEMORY_SCOPE_AGENT);
        }
        const f32x2 c2x = (f32x2){cx, cx};
        const f32x2 c2y = (f32x2){cy, cy};
        const f32x2 c2z = (f32x2){cz, cz};
#pragma unroll
        for (int i = 0; i < 8; ++i) {
            const f32x2 dx = px[i] - c2x;
            const f32x2 dy = py[i] - c2y;
            const f32x2 dz = pz[i] - c2z;
            const f32x2 s = dx * dx + dy * dy;   // pk_mul + pk_add (no fma)
            const f32x2 d = s + dz * dz;
            dist[i].x = fminf(dist[i].x, d.x);
            dist[i].y = fminf(dist[i].y, d.y);
        }
        float dv[16];
#pragma unroll
        for (int i = 0; i < 8; ++i) { dv[2 * i] = dist[i].x; dv[2 * i + 1] = dist[i].y; }
        float m8[8], m4[4], bv;
#pragma unroll
        for (int i = 0; i < 8; ++i) m8[i] = fmaxf(dv[i], dv[i + 8]);
#pragma unroll
        for (int i = 0; i < 4; ++i) m4[i] = fmaxf(m8[i], m8[i + 4]);
        bv = fmaxf(fmaxf(m4[0], m4[1]), fmaxf(m4[2], m4[3]));
        int bj = 15;
#pragma unroll
        for (int i = 14; i >= 0; --i) bj = (dv[i] == bv) ? i : bj;
        const int myidx = t * 16 + bj;

        const float wmax = wave_max_dpp(bv);
        const u64 mask = __ballot(bv == wmax);
        const int fl = (int)__builtin_ctzll(mask);
        const int widx = __builtin_amdgcn_readlane(myidx, fl);

        const int pp = k & 1;
        if (lane == 0)
            skey[pp * 4 + wave] =
                ((u64)__float_as_uint(wmax) << 32) | (unsigned)(4095 - widx);
        __syncthreads();
        const ulonglong2 ka = *reinterpret_cast<const ulonglong2*>(&skey[pp * 4]);
        const ulonglong2 kb = *reinterpret_cast<const ulonglong2*>(&skey[pp * 4 + 2]);
        const u64 m01 = (ka.x > ka.y) ? ka.x : ka.y;
        const u64 m23 = (kb.x > kb.y) ? kb.x : kb.y;
        const u64 mm = (m01 > m23) ? m01 : m23;
        far = 4095 - (int)(unsigned)(mm & 0xffffffffull);

        if (t == 0 && (k & 31) == 31)
            __hip_atomic_store(&progress[b * 32], k + 1, __ATOMIC_RELEASE,
                               __HIP_MEMORY_SCOPE_AGENT);
    }
}

// ---------------------------------------------------------------------------
extern "C" void kernel_launch(void* const* d_in, const int* in_sizes, int n_in,
                              void* d_out, int out_size, void* d_ws, size_t ws_size,
                              hipStream_t stream) {
    (void)in_sizes; (void)n_in; (void)out_size; (void)ws_size;
    const float* xyz = (const float*)d_in[0];
    const float* points = (const float*)d_in[1];
    WPack pack;
    int p = 2;
    for (int L = 0; L < 9; ++L) {
        pack.w[L] = (const float*)d_in[p++];
        pack.b[L] = (const float*)d_in[p++];
    }
    float* newxyz = (float*)d_out;                  // 8*1024*3
    float* outfeat = (float*)d_out + 8 * 1024 * 3;  // 8*1024*320

    char* ws = (char*)d_ws;
    unsigned short* wprep = (unsigned short*)ws;       // 54528 bf16 = 109056 B
    float* bprep = (float*)(ws + 109056);              // 672 f32 = 2688 B
    int* progress = (int*)(ws + 111744);               // 8 flags, 128B-strided

    hipMemsetAsync(progress, 0, 1024, stream);
    prep_kernel<<<dim3(9), dim3(256), 0, stream>>>(pack, wprep, bprep);

    int occ = 0;
    hipOccupancyMaxActiveBlocksPerMultiprocessor(
        &occ, reinterpret_cast<const void*>(fused_kernel), 256, 0);
    if (occ < 1) occ = 1;
    int G = occ * 256;                  // all blocks resident at launch
    if (G < 16) G = 16;
    int W = G - 8;
    fused_kernel<<<dim3(G), dim3(256), 0, stream>>>(
        xyz, points, newxyz, outfeat, wprep, bprep, progress, W);
}

// Round 11
// 986.781 us; speedup vs baseline: 1.0031x; 1.0031x over previous
//
#include <hip/hip_runtime.h>
#include <hip/hip_bf16.h>
#include <stdint.h>

typedef unsigned long long u64;
typedef __attribute__((ext_vector_type(8))) short bf16x8;   // 8 bf16 = 4 VGPRs
typedef __attribute__((ext_vector_type(4))) float f32x4;
typedef __attribute__((ext_vector_type(2))) float f32x2;    // v_pk_*_f32 pair

__device__ __forceinline__ unsigned short f2bf(float f) {
    unsigned x = __float_as_uint(f);
    unsigned r = (x + 0x7fffu + ((x >> 16) & 1u)) >> 16;   // RNE
    return (unsigned short)r;
}

// 8 f32 -> bf16x8 via packed RNE converts (v_cvt_pk_bf16_f32).
__device__ __forceinline__ bf16x8 cvt8(float4 a, float4 b) {
    union { bf16x8 v; __hip_bfloat162 h[4]; } u;
    u.h[0] = __float22bfloat162_rn({a.x, a.y});
    u.h[1] = __float22bfloat162_rn({a.z, a.w});
    u.h[2] = __float22bfloat162_rn({b.x, b.y});
    u.h[3] = __float22bfloat162_rn({b.z, b.w});
    return u.v;
}

// Wave64 max-reduce of a non-negative f32 at VALU speed (DPP, no LDS hops).
__device__ __forceinline__ float wave_max_dpp(float v) {
#define DPP_MAX_STEP(ctrl)                                                     \
    v = fmaxf(v, __int_as_float(__builtin_amdgcn_update_dpp(                   \
               0, __float_as_int(v), (ctrl), 0xf, 0xf, true)))
    DPP_MAX_STEP(0xB1);   // quad_perm xor1
    DPP_MAX_STEP(0x4E);   // quad_perm xor2
    DPP_MAX_STEP(0x141);  // row_half_mirror xor4
    DPP_MAX_STEP(0x140);  // row_mirror xor8
    DPP_MAX_STEP(0x142);  // row_bcast15
    DPP_MAX_STEP(0x143);  // row_bcast31
#undef DPP_MAX_STEP
    return __int_as_float(__builtin_amdgcn_readlane(__float_as_int(v), 63));
}

struct WPack { const float* w[9]; const float* b[9]; };

// ---------------------------------------------------------------------------
// Kernel 0: weight prep (separate launch => results are plain-cacheable in
// every XCD L2 via the kernel-boundary release/acquire).
// ---------------------------------------------------------------------------
__global__ __launch_bounds__(256) void prep_kernel(WPack p,
                                                   unsigned short* __restrict__ wout,
                                                   float* __restrict__ bout) {
    constexpr int cin[9]  = {67, 32, 32,  67, 64, 64,  67, 64, 96};
    constexpr int cout[9] = {32, 32, 64,  64, 64, 128, 64, 96, 128};
    constexpr int sw[9]   = {104, 40, 40, 104, 72, 72, 104, 72, 104};
    constexpr int woff[9] = {0, 3328, 4608, 7168, 13824, 18432, 27648, 34304, 41216};
    constexpr int boff[9] = {0, 32, 64, 128, 192, 256, 384, 448, 544};
    const int L = blockIdx.x;
    const float* w = p.w[L];
    const int ci = cin[L], co = cout[L], s = sw[L];
    unsigned short* dst = wout + woff[L];
    for (int e = threadIdx.x; e < co * s; e += 256) {
        const int n = e / s, k = e % s;
        dst[e] = (k < ci) ? f2bf(w[(size_t)k * co + n]) : (unsigned short)0;
    }
    for (int e = threadIdx.x; e < co; e += 256) bout[boff[L] + e] = p.b[L][e];
}

// ---------------------------------------------------------------------------
// Single-radius ball query into LDS (one wave). Bit-exact predicate vs numpy.
// ---------------------------------------------------------------------------
template <int NS>
__device__ __forceinline__ void ballq_one(const float* __restrict__ base,
                                          float cx, float cy, float cz, float R2,
                                          unsigned short* __restrict__ out, int lane) {
    int cnt = 0, f = 0;
    const u64 lower = (((u64)1) << lane) - 1;
    for (int it = 0; it < 64; ++it) {
        const int j = it * 64 + lane;
        const float* p = base + j * 3;
        const float dx = p[0] - cx, dy = p[1] - cy, dz = p[2] - cz;
        const float d2 = __fadd_rn(__fadd_rn(__fmul_rn(dx, dx), __fmul_rn(dy, dy)),
                                   __fmul_rn(dz, dz));
        const bool pr = d2 < R2;
        const u64 m = __ballot(pr);
        if (cnt == 0 && m) f = it * 64 + __builtin_ctzll(m);
        const int pos = cnt + (int)__builtin_popcountll(m & lower);
        if (pr && pos < NS) out[pos] = (unsigned short)j;
        cnt += (int)__builtin_popcountll(m);
        if (cnt >= NS) break;
    }
    for (int pos = cnt + lane; pos < NS; pos += 64) out[pos] = (unsigned short)f;
}

// ---------------------------------------------------------------------------
// Layer 1: A-fragments direct from global points; K = 96 (67 real + pad).
// ---------------------------------------------------------------------------
template <int MW, int Cout, int SOUT>
__device__ __forceinline__ void layer1_direct(
    const float* __restrict__ pts, const float* __restrict__ xyzb,
    const unsigned short* __restrict__ idxb,
    float ncx, float ncy, float ncz,
    const unsigned short* __restrict__ Wg, const float* __restrict__ bg,
    unsigned short* __restrict__ dst, int lane, int mslice) {
    constexpr int SW = 104;
    constexpr int MT = MW / 16;
    constexpr int NT = Cout / 16;
    const int ml = lane & 15;
    const int quad = lane >> 4;

    bf16x8 afr[MT][3];
#pragma unroll
    for (int mt = 0; mt < MT; ++mt) {
        const int row = mslice * MW + mt * 16 + ml;
        const int id = idxb[row] & 4095;
        const float* rb = pts + ((size_t)id << 6) + quad * 8;
        const float4* r4 = reinterpret_cast<const float4*>(rb);
        afr[mt][0] = cvt8(r4[0], r4[1]);
        const float4* r4b = reinterpret_cast<const float4*>(rb + 32);
        afr[mt][1] = cvt8(r4b[0], r4b[1]);
        union { bf16x8 v; unsigned short h[8]; } tg;
        tg.v = (bf16x8)(short)0;
        if (quad == 0) {
            const float* pz = xyzb + (size_t)id * 3;
            tg.h[0] = f2bf(pz[0] - ncx);
            tg.h[1] = f2bf(pz[1] - ncy);
            tg.h[2] = f2bf(pz[2] - ncz);
        }
        afr[mt][2] = tg.v;
    }

    f32x4 acc[MT][NT];
#pragma unroll
    for (int mt = 0; mt < MT; ++mt)
#pragma unroll
        for (int nt = 0; nt < NT; ++nt) acc[mt][nt] = (f32x4){0.f, 0.f, 0.f, 0.f};

#pragma unroll
    for (int ks = 0; ks < 3; ++ks) {
        bf16x8 bfr[NT];
#pragma unroll
        for (int nt = 0; nt < NT; ++nt)
            bfr[nt] = *reinterpret_cast<const bf16x8*>(
                Wg + (nt * 16 + ml) * SW + ks * 32 + quad * 8);
#pragma unroll
        for (int mt = 0; mt < MT; ++mt)
#pragma unroll
            for (int nt = 0; nt < NT; ++nt)
                acc[mt][nt] = __builtin_amdgcn_mfma_f32_16x16x32_bf16(
                    afr[mt][ks], bfr[nt], acc[mt][nt], 0, 0, 0);
    }

#pragma unroll
    for (int nt = 0; nt < NT; ++nt) {
        const int col = nt * 16 + ml;
        const float bv = bg[col];
#pragma unroll
        for (int mt = 0; mt < MT; ++mt)
#pragma unroll
            for (int r = 0; r < 4; ++r) {
                const float v = fmaxf(acc[mt][nt][r] + bv, 0.0f);
                dst[(mslice * MW + mt * 16 + quad * 4 + r) * SOUT + col] = f2bf(v);
            }
    }
}

// ---------------------------------------------------------------------------
// Layers 2/3: A from LDS, B + bias from prepped global.
// LAST+DIRECT: quad0 lanes write outfeat straight (WPG==1 branches).
// LAST+!DIRECT: atomicMax into LDS Mx (WPG==4 cross-wave merge).
// ---------------------------------------------------------------------------
template <int MW, int Kp, int Cout, int SIN, int SW, int SOUT, bool LAST, bool DIRECT>
__device__ __forceinline__ void layer_lds(const unsigned short* __restrict__ src,
                                          unsigned short* __restrict__ dst,
                                          const unsigned short* __restrict__ Wg,
                                          const float* __restrict__ bg,
                                          float* __restrict__ Mx,
                                          float* __restrict__ outp,
                                          int lane, int mslice) {
    constexpr int MT = MW / 16;
    constexpr int NT = Cout / 16;
    const int ml = lane & 15;
    const int quad = lane >> 4;

    f32x4 acc[MT][NT];
#pragma unroll
    for (int mt = 0; mt < MT; ++mt)
#pragma unroll
        for (int nt = 0; nt < NT; ++nt) acc[mt][nt] = (f32x4){0.f, 0.f, 0.f, 0.f};

#pragma unroll
    for (int ks = 0; ks < Kp; ks += 32) {
        bf16x8 afr[MT], bfr[NT];
#pragma unroll
        for (int mt = 0; mt < MT; ++mt)
            afr[mt] = *reinterpret_cast<const bf16x8*>(
                src + (mslice * MW + mt * 16 + ml) * SIN + ks + quad * 8);
#pragma unroll
        for (int nt = 0; nt < NT; ++nt)
            bfr[nt] = *reinterpret_cast<const bf16x8*>(
                Wg + (nt * 16 + ml) * SW + ks + quad * 8);
#pragma unroll
        for (int mt = 0; mt < MT; ++mt)
#pragma unroll
            for (int nt = 0; nt < NT; ++nt)
                acc[mt][nt] = __builtin_amdgcn_mfma_f32_16x16x32_bf16(
                    afr[mt], bfr[nt], acc[mt][nt], 0, 0, 0);
    }

#pragma unroll
    for (int nt = 0; nt < NT; ++nt) {
        const int col = nt * 16 + ml;
        const float bv = bg[col];
        if constexpr (!LAST) {
#pragma unroll
            for (int mt = 0; mt < MT; ++mt)
#pragma unroll
                for (int r = 0; r < 4; ++r) {
                    const float v = fmaxf(acc[mt][nt][r] + bv, 0.0f);
                    dst[(mslice * MW + mt * 16 + quad * 4 + r) * SOUT + col] = f2bf(v);
                }
        } else {
            float mx = 0.0f;   // relu floor folds into the max
#pragma unroll
            for (int mt = 0; mt < MT; ++mt)
#pragma unroll
                for (int r = 0; r < 4; ++r) mx = fmaxf(mx, acc[mt][nt][r] + bv);
            mx = fmaxf(mx, __shfl_xor(mx, 16, 64));
            mx = fmaxf(mx, __shfl_xor(mx, 32, 64));
            if constexpr (DIRECT) {
                if (quad == 0) outp[col] = mx;
            } else {
                if (quad == 0)
                    atomicMax(reinterpret_cast<int*>(Mx + col), __float_as_int(mx));
            }
        }
    }
}

// ---------------------------------------------------------------------------
// One work item: WPG==1 -> 4 groups, 1 wave each; WPG==4 -> 1 group, 4 waves.
// Inline ballq into LDS + 3-layer MLP + pooled write.
// ---------------------------------------------------------------------------
template <int NS, int C1, int C2, int C3, int WPG, int CH_OFF>
__device__ __forceinline__ void do_item(
    char* smem, const float* __restrict__ xyz, const float* __restrict__ points,
    float* newxyz, float* __restrict__ outfeat,
    const unsigned short* __restrict__ wg1, const unsigned short* __restrict__ wg2,
    const unsigned short* __restrict__ wg3,
    const float* __restrict__ bg1, const float* __restrict__ bg2,
    const float* __restrict__ bg3,
    float R2, int b, int p, int tid, int lane, int wave) {
    constexpr int SB = C1 + 8;
    constexpr int SC = C2 + 8;
    constexpr int MW = NS / WPG;
    unsigned short* idxb = (unsigned short*)smem;                    // <=1KB
    unsigned short* Bb = (unsigned short*)(smem + 1024);             // <=18432B
    unsigned short* Cb = (unsigned short*)(smem + 1024 + 18432);     // <=26624B
    float* Mx = (float*)(smem + 1024 + 18432 + 26624);               // <=512B

    const int gl = (WPG == 1) ? wave : 0;
    const int mslice = (WPG == 1) ? 0 : wave;
    const int g = b * 1024 + ((WPG == 1) ? p * 4 + wave : p);
    const float* base = xyz + (size_t)b * 12288;

    // centroid: LLC reads (producer used agent-scope stores)
    const float ncx = __hip_atomic_load(&newxyz[(size_t)g * 3 + 0],
                                        __ATOMIC_RELAXED, __HIP_MEMORY_SCOPE_AGENT);
    const float ncy = __hip_atomic_load(&newxyz[(size_t)g * 3 + 1],
                                        __ATOMIC_RELAXED, __HIP_MEMORY_SCOPE_AGENT);
    const float ncz = __hip_atomic_load(&newxyz[(size_t)g * 3 + 2],
                                        __ATOMIC_RELAXED, __HIP_MEMORY_SCOPE_AGENT);

    // ball query into LDS (WPG==4: all 4 waves write identical values — benign)
    unsigned short* myidx = idxb + gl * NS;
    ballq_one<NS>(base, ncx, ncy, ncz, R2, myidx, lane);
    if (WPG == 4)
        for (int e = tid; e < C3; e += 256) Mx[e] = 0.0f;
    __syncthreads();

    float* outp = outfeat + (size_t)g * 320 + CH_OFF;
    layer1_direct<MW, C1, SB>(points + ((size_t)b << 18), base, myidx,
                              ncx, ncy, ncz, wg1, bg1, Bb + gl * NS * SB,
                              lane, mslice);
    layer_lds<MW, C1, C2, SB, C1 + 8, SC, false, false>(
        Bb + gl * NS * SB, Cb + gl * NS * SC, wg2, bg2, nullptr, nullptr,
        lane, mslice);
    layer_lds<MW, C2, C3, SC, C2 + 8, 0, true, (WPG == 1)>(
        Cb + gl * NS * SC, nullptr, wg3, bg3, Mx, outp, lane, mslice);

    if (WPG == 4) {
        __syncthreads();
        for (int e = tid; e < C3; e += 256) outp[e] = Mx[e];
    }
}

// ---------------------------------------------------------------------------
// Fused pipeline kernel, ONE BLOCK PER CU (grid = 256): R10 post-mortem — at
// 3 blocks/CU the worker siblings stretched the latency-critical FPS chain
// 1.66x. With 256 blocks the dispatcher gives every block its own CU: 8 FPS
// producers run contention-free; 248 workers (~150 µs busy each) hide inside
// the ~540 µs FPS shadow with 3x slack.
// ---------------------------------------------------------------------------
__global__ __launch_bounds__(256) void fused_kernel(
    const float* __restrict__ xyz, const float* __restrict__ points,
    float* newxyz, float* __restrict__ outfeat,
    const unsigned short* __restrict__ wprep, const float* __restrict__ bprep,
    int* progress, int W) {
#pragma clang fp contract(off)
    __shared__ __align__(16) char smem[49664];
    const int tid = threadIdx.x;
    const int lane = tid & 63;
    const int wave = tid >> 6;

    if (blockIdx.x >= 8) {   // ================= worker =================
        const int wid = blockIdx.x - 8;
        for (int s = wid; s < 12288; s += W) {
            int br, b, p;
            if (s < 6144) {
                p = s / 24;
                const int r = s % 24;
                br = r >> 3;
                b = r & 7;
            } else {
                const int q = s - 6144;
                p = 256 + (q >> 3);
                b = q & 7;
                br = 2;
            }
            const int kmax = (br == 2) ? p : p * 4 + 3;
            while (__hip_atomic_load(&progress[b * 32], __ATOMIC_RELAXED,
                                     __HIP_MEMORY_SCOPE_AGENT) <= kmax)
                __builtin_amdgcn_s_sleep(32);
            __atomic_signal_fence(__ATOMIC_SEQ_CST);   // no load hoisting

            if (br == 0)
                do_item<16, 32, 32, 64, 1, 0>(smem, xyz, points, newxyz, outfeat,
                    wprep + 0, wprep + 3328, wprep + 4608,
                    bprep + 0, bprep + 32, bprep + 64,
                    0.01f, b, p, tid, lane, wave);
            else if (br == 1)
                do_item<32, 64, 64, 128, 1, 64>(smem, xyz, points, newxyz, outfeat,
                    wprep + 7168, wprep + 13824, wprep + 18432,
                    bprep + 128, bprep + 192, bprep + 256,
                    0.04f, b, p, tid, lane, wave);
            else
                do_item<128, 64, 96, 128, 4, 192>(smem, xyz, points, newxyz, outfeat,
                    wprep + 27648, wprep + 34304, wprep + 41216,
                    bprep + 384, bprep + 448, bprep + 544,
                    0.16f, b, p, tid, lane, wave);
            __syncthreads();   // LDS reuse across items
        }
        return;
    }

    // ================= FPS producer (R7-proven structure) =================
    const int b = blockIdx.x;
    const int t = tid;
    float* xs = (float*)smem;
    float* ys = xs + 4096;
    float* zs = ys + 4096;
    u64* skey = (u64*)(smem + 49152);   // [2][4]

    f32x2 px[8], py[8], pz[8], dist[8];
    {
        union { float4 v[12]; float f[48]; } u;
        const float4* src =
            reinterpret_cast<const float4*>(xyz + (size_t)b * 12288) + t * 12;
#pragma unroll
        for (int w = 0; w < 12; ++w) u.v[w] = src[w];
#pragma unroll
        for (int i = 0; i < 8; ++i) {
            px[i] = (f32x2){u.f[6 * i + 0], u.f[6 * i + 3]};
            py[i] = (f32x2){u.f[6 * i + 1], u.f[6 * i + 4]};
            pz[i] = (f32x2){u.f[6 * i + 2], u.f[6 * i + 5]};
            dist[i] = (f32x2){1e10f, 1e10f};
            const int j = t * 16 + 2 * i;
            xs[j] = px[i].x; xs[j + 1] = px[i].y;
            ys[j] = py[i].x; ys[j + 1] = py[i].y;
            zs[j] = pz[i].x; zs[j + 1] = pz[i].y;
        }
    }
    __syncthreads();

    int far = 0;
    for (int k = 0; k < 1024; ++k) {
        const float cx = xs[far], cy = ys[far], cz = zs[far];
        if (t == 0) {
            const size_t o = ((size_t)b * 1024 + k) * 3;
            __hip_atomic_store(&newxyz[o + 0], cx, __ATOMIC_RELAXED,
                               __HIP_MEMORY_SCOPE_AGENT);
            __hip_atomic_store(&newxyz[o + 1], cy, __ATOMIC_RELAXED,
                               __HIP_MEMORY_SCOPE_AGENT);
            __hip_atomic_store(&newxyz[o + 2], cz, __ATOMIC_RELAXED,
                               __HIP_MEMORY_SCOPE_AGENT);
        }
        const f32x2 c2x = (f32x2){cx, cx};
        const f32x2 c2y = (f32x2){cy, cy};
        const f32x2 c2z = (f32x2){cz, cz};
#pragma unroll
        for (int i = 0; i < 8; ++i) {
            const f32x2 dx = px[i] - c2x;
            const f32x2 dy = py[i] - c2y;
            const f32x2 dz = pz[i] - c2z;
            const f32x2 s = dx * dx + dy * dy;   // pk_mul + pk_add (no fma)
            const f32x2 d = s + dz * dz;
            dist[i].x = fminf(dist[i].x, d.x);
            dist[i].y = fminf(dist[i].y, d.y);
        }
        float dv[16];
#pragma unroll
        for (int i = 0; i < 8; ++i) { dv[2 * i] = dist[i].x; dv[2 * i + 1] = dist[i].y; }
        float m8[8], m4[4], bv;
#pragma unroll
        for (int i = 0; i < 8; ++i) m8[i] = fmaxf(dv[i], dv[i + 8]);
#pragma unroll
        for (int i = 0; i < 4; ++i) m4[i] = fmaxf(m8[i], m8[i + 4]);
        bv = fmaxf(fmaxf(m4[0], m4[1]), fmaxf(m4[2], m4[3]));
        int bj = 15;
#pragma unroll
        for (int i = 14; i >= 0; --i) bj = (dv[i] == bv) ? i : bj;
        const int myidx = t * 16 + bj;

        const float wmax = wave_max_dpp(bv);
        const u64 mask = __ballot(bv == wmax);
        const int fl = (int)__builtin_ctzll(mask);
        const int widx = __builtin_amdgcn_readlane(myidx, fl);

        const int pp = k & 1;
        if (lane == 0)
            skey[pp * 4 + wave] =
                ((u64)__float_as_uint(wmax) << 32) | (unsigned)(4095 - widx);
        __syncthreads();
        const ulonglong2 ka = *reinterpret_cast<const ulonglong2*>(&skey[pp * 4]);
        const ulonglong2 kb = *reinterpret_cast<const ulonglong2*>(&skey[pp * 4 + 2]);
        const u64 m01 = (ka.x > ka.y) ? ka.x : ka.y;
        const u64 m23 = (kb.x > kb.y) ? kb.x : kb.y;
        const u64 mm = (m01 > m23) ? m01 : m23;
        far = 4095 - (int)(unsigned)(mm & 0xffffffffull);

        if (t == 0 && (k & 31) == 31)
            __hip_atomic_store(&progress[b * 32], k + 1, __ATOMIC_RELEASE,
                               __HIP_MEMORY_SCOPE_AGENT);
    }
}

// ---------------------------------------------------------------------------
extern "C" void kernel_launch(void* const* d_in, const int* in_sizes, int n_in,
                              void* d_out, int out_size, void* d_ws, size_t ws_size,
                              hipStream_t stream) {
    (void)in_sizes; (void)n_in; (void)out_size; (void)ws_size;
    const float* xyz = (const float*)d_in[0];
    const float* points = (const float*)d_in[1];
    WPack pack;
    int p = 2;
    for (int L = 0; L < 9; ++L) {
        pack.w[L] = (const float*)d_in[p++];
        pack.b[L] = (const float*)d_in[p++];
    }
    float* newxyz = (float*)d_out;                  // 8*1024*3
    float* outfeat = (float*)d_out + 8 * 1024 * 3;  // 8*1024*320

    char* ws = (char*)d_ws;
    unsigned short* wprep = (unsigned short*)ws;       // 54528 bf16 = 109056 B
    float* bprep = (float*)(ws + 109056);              // 672 f32 = 2688 B
    int* progress = (int*)(ws + 111744);               // 8 flags, 128B-strided

    hipMemsetAsync(progress, 0, 1024, stream);
    prep_kernel<<<dim3(9), dim3(256), 0, stream>>>(pack, wprep, bprep);

    // Grid = 256: one block per CU (see fused_kernel comment).
    const int G = 256;
    const int W = G - 8;
    fused_kernel<<<dim3(G), dim3(256), 0, stream>>>(
        xyz, points, newxyz, outfeat, wprep, bprep, progress, W);
}